// Round 5
// baseline (189.489 us; speedup 1.0000x reference)
//
#include <hip/hip_runtime.h>
#include <math.h>

#define DD 64
#define CC 128
#define HH 512
#define BATCH 4096

typedef __attribute__((ext_vector_type(2))) float f32x2;
typedef unsigned long long u64;

__device__ __forceinline__ f32x2 splat2(float x) { f32x2 v; v[0] = x; v[1] = x; return v; }
__device__ __forceinline__ f32x2 lo2(float4 v) { f32x2 r; r[0] = v.x; r[1] = v.y; return r; }
__device__ __forceinline__ f32x2 hi2(float4 v) { f32x2 r; r[0] = v.z; r[1] = v.w; return r; }

// packed FMA with the one legal scalar source: src0 is an SGPR pair {h,h}.
__device__ __forceinline__ f32x2 pk_fma_s(u64 hpair, f32x2 b, f32x2 c) {
    f32x2 d;
    asm("v_pk_fma_f32 %0, %1, %2, %3" : "=v"(d) : "s"(hpair), "v"(b), "v"(c));
    return d;
}

__device__ __forceinline__ float fast_softplus(float x) {
    float t = exp2f(-fabsf(x) * 1.44269504f);
    return fmaxf(x, 0.f) + 0.69314718f * log2f(1.f + t);
}

// wave-uniform broadcast via v_readlane (SGPR result)
__device__ __forceinline__ float bcast(float x, int l) {
    return __int_as_float(__builtin_amdgcn_readlane(__float_as_int(x), l));
}
// broadcast to an SGPR pair {x,x} for pk_fma_s (pair build is SALU, co-issues)
__device__ __forceinline__ u64 rl_pair(float x, int l) {
    unsigned u = (unsigned)__builtin_amdgcn_readlane(__float_as_int(x), l);
    return ((u64)u << 32) | u;
}

typedef const __attribute__((address_space(1))) void* as1_cptr;
typedef __attribute__((address_space(3))) void* as3_ptr;
typedef const __attribute__((address_space(3))) float* as3c;
__device__ __forceinline__ void glds16(const float* g, float* l) {
    __builtin_amdgcn_global_load_lds((as1_cptr)g, (as3_ptr)l, 16, 0, 0);
}

// volatile asm LDS reads: the compiler CANNOT sink these (rounds 1-4: every
// C-level hoist was re-sunk, VGPR stuck at 40-92, ds_read latency exposed
// ~30x per iteration). One cluster -> one lgkmcnt(0) exposure.
__device__ __forceinline__ float4 ldsb128(const float* p) {
    float4 r;
    asm volatile("ds_read_b128 %0, %1" : "=v"(r) : "v"((as3c)p));
    return r;
}
// reads {p[0], p[64]}  (w3 pair: W3[k,lane], W3[k,64+lane])
__device__ __forceinline__ f32x2 ldsr2(const float* p) {
    f32x2 r;
    asm volatile("ds_read2_b32 %0, %1 offset0:0 offset1:64" : "=v"(r) : "v"((as3c)p));
    return r;
}

// One block = 4 waves x R=2 rows = 8 batch rows; grid 512 -> 2 blocks/CU.
// Geometry rationale: R=1/16-wave (R4) is LDS-read-pipe-bound (400 KB/CU/iter
// = 3200cy of the 3840cy window: weight reads replicated per wave). R=2 at
// 8 waves/CU halves that to 42% and keeps cross-block drain overlap (lost in
// R3's merged block). R2 showed this geometry's limit is exposed ds_read
// latency at 2 waves/SIMD -> fixed here with the volatile-asm read cluster.
__global__ __launch_bounds__(256, 2) void made_sample(
    const float* __restrict__ ctx,   // (B, C)
    const float* __restrict__ eps,   // (B, D)
    const float* __restrict__ W1,    // (D+C, H)
    const float* __restrict__ b1,    // (H)
    const float* __restrict__ W2,    // (H, H)
    const float* __restrict__ b2,    // (H)
    const float* __restrict__ W3,    // (H, 2D)
    const float* __restrict__ b3,    // (2D)
    float* __restrict__ out)         // (B, D)
{
    const int lane  = threadIdx.x & 63;
    const int w     = threadIdx.x >> 6;          // wave 0..3
    const int rbase = blockIdx.x * 8 + w * 2;    // 2 batch rows per wave
    const int jbase = 8 * lane;

    __shared__ float sbuf[2][10 * HH];           // 2 x 20 KB (slots: 9 W2 + 1 W1)
    __shared__ float w3sb[2][5 * 256];           // 2 x 5 KB  (5 pairs of W3 rows)

    int deg[8];
    #pragma unroll
    for (int u = 0; u < 8; ++u) deg[u] = (jbase + u) % 63 + 1;

    auto stage_row = [&](const float* src, float* dst) {
        glds16(src + lane * 8,     dst);
        glds16(src + lane * 8 + 4, dst + 256);
    };
    // stage W3 rows k0,k1 (128 floats each) into one 1KB pair slot:
    // lanes 0..31 carry row k0, lanes 32..63 row k1.
    auto stage_w3pair = [&](int k0, int k1, float* dst) {
        const float* g = (lane < 32) ? (W3 + k0 * (2 * DD) + lane * 4)
                                     : (W3 + k1 * (2 * DD) + (lane - 32) * 4);
        glds16(g, dst);
    };

    f32x2 p1[2][4], p2[2][4];
    #pragma unroll
    for (int j = 0; j < 4; ++j) {
        f32x2 t1, t2;
        t1[0] = b1[jbase + 2 * j]; t1[1] = b1[jbase + 2 * j + 1];
        t2[0] = b2[jbase + 2 * j]; t2[1] = b2[jbase + 2 * j + 1];
        p1[0][j] = t1; p1[1][j] = t1;
        p2[0][j] = t2; p2[1][j] = t2;
    }
    // (d) accumulators, split even/odd-t chains to halve dependency depth
    f32x2 accA[2], accB[2];
    accA[0] = splat2(0.f); accA[1] = splat2(0.f);
    accB[0] = splat2(0.f); accB[1] = splat2(0.f);

    float ca[2], cb[2], ep[2];
    #pragma unroll
    for (int r = 0; r < 2; ++r) {
        ca[r] = ctx[(rbase + r) * CC + lane];
        cb[r] = ctx[(rbase + r) * CC + 64 + lane];
        ep[r] = eps[(rbase + r) * DD + lane];
    }
    const float b3m = b3[lane];        // bias for mean col `lane`
    const float b3p = b3[64 + lane];   // bias for prescale col `lane`

    // ctx chunk ch: W1 rows DD+8ch..DD+8ch+7 -> slots 0..7 (2 rows per wave)
    auto stage_ctx = [&](int ch, float* buf) {
        stage_row(W1 + (DD + 8 * ch + 2 * w) * HH,     buf + (2 * w) * HH);
        stage_row(W1 + (DD + 8 * ch + 2 * w + 1) * HH, buf + (2 * w + 1) * HH);
    };
    // staging for main step `in`, spread over 4 waves:
    //   wave w: W2 rows basen+63*w -> slot w, basen+63*(4+w) -> slot 4+w
    //   wave 0: + W2 row basen+504 -> slot 8          (iff basen<8)
    //   wave 1: + W1 row `in` -> slot 9
    //   wave w: W3 pair p=w; wave 2: + pair 4          (iff basen<8)
    auto stage_step = [&](int in, float* buf, float* w3buf) {
        if (in == 0) {                       // step 0 needs only W1 row 0
            if (w == 1) stage_row(W1, buf + 9 * HH);
            return;
        }
        const int basen = in - 1;
        const bool h9n = basen < 8;
        stage_row(W2 + (basen + 63 * w) * HH,       buf + w * HH);
        stage_row(W2 + (basen + 63 * (4 + w)) * HH, buf + (4 + w) * HH);
        if (w == 0 && h9n) stage_row(W2 + (basen + 504) * HH, buf + 8 * HH);
        if (w == 1) stage_row(W1 + in * HH, buf + 9 * HH);
        stage_w3pair(basen + 63 * (2 * w), basen + 63 * (2 * w + 1),
                     w3buf + w * 256);
        if (w == 2 && h9n)
            stage_w3pair(basen + 504, basen + 504, w3buf + 4 * 256);
    };

    // ---- context init: pre1 += ctx @ W1[D:,:], 16 chunks of 8 rows ----
    stage_ctx(0, sbuf[0]);
    __syncthreads();
    #pragma unroll 1
    for (int ch = 0; ch < 16; ++ch) {
        float* cur = sbuf[ch & 1];
        if (ch < 15) stage_ctx(ch + 1, sbuf[(ch + 1) & 1]);
        else         stage_step(0, sbuf[0], w3sb[0]);   // (16)&1==0: parity OK
        // pinned read cluster: 16 ds_read_b128, one lgkmcnt exposure
        const float* lb = cur + lane * 4;
        float4 cwL[8], cwH[8];
        #pragma unroll
        for (int q = 0; q < 8; ++q) {
            cwL[q] = ldsb128(lb + q * HH);
            cwH[q] = ldsb128(lb + q * HH + 256);
        }
        asm volatile("s_waitcnt lgkmcnt(0)" ::: "memory");
        __builtin_amdgcn_sched_barrier(0);
        #pragma unroll
        for (int q = 0; q < 8; ++q) {
            const int c = 8 * ch + q;
            #pragma unroll
            for (int r = 0; r < 2; ++r) {
                const u64 cvp = rl_pair((ch < 8) ? ca[r] : cb[r], c & 63);
                p1[r][0] = pk_fma_s(cvp, lo2(cwL[q]), p1[r][0]);
                p1[r][1] = pk_fma_s(cvp, hi2(cwL[q]), p1[r][1]);
                p1[r][2] = pk_fma_s(cvp, lo2(cwH[q]), p1[r][2]);
                p1[r][3] = pk_fma_s(cvp, hi2(cwH[q]), p1[r][3]);
            }
        }
        __syncthreads();
    }

    float z[2] = {0.f, 0.f};

    // ---- autoregressive main loop ----
    #pragma unroll 1
    for (int i = 0; i < DD; ++i) {
        float* cur = sbuf[i & 1];
        const float* w3s = w3sb[i & 1];

        // issue next-step staging first (vmcnt countdown starts earliest)
        if (i < 63) stage_step(i + 1, sbuf[(i + 1) & 1], w3sb[(i + 1) & 1]);

        // ---- pinned LDS read cluster: everything this iteration needs ----
        const float* lb = cur + lane * 4;
        float4 wL[9], wH[9];
        f32x2 w3v[9];
        if (i > 0) {
            #pragma unroll
            for (int t = 0; t < 9; ++t) {
                wL[t] = ldsb128(lb + t * HH);
                wH[t] = ldsb128(lb + t * HH + 256);
            }
            #pragma unroll
            for (int t = 0; t < 9; ++t) w3v[t] = ldsr2(w3s + t * 128 + lane);
        }
        const float4 w1L = ldsb128(lb + 9 * HH);
        const float4 w1H = ldsb128(lb + 9 * HH + 256);
        asm volatile("s_waitcnt lgkmcnt(0)" ::: "memory");
        __builtin_amdgcn_sched_barrier(0);

        if (i > 0) {                      // i==0: no unit has deg==0, all h==0
            const int base = i - 1;
            const bool h9 = base < 8;     // 9th finalizing unit exists (i<=8)

            // (a) one-hot select finalized h1 (deg==i) via add-tree (depth 3)
            float m[2];
            #pragma unroll
            for (int r = 0; r < 2; ++r) {
                float s[8];
                #pragma unroll
                for (int u = 0; u < 8; ++u)
                    s[u] = (deg[u] == i) ? p1[r][u >> 1][u & 1] : 0.f;
                const float sv = ((s[0] + s[1]) + (s[2] + s[3]))
                               + ((s[4] + s[5]) + (s[6] + s[7]));
                m[r] = fmaxf(sv, 0.f);
            }

            // (b) rank update of pre2 (packed FMA, SGPR-pair h operand)
            #pragma unroll
            for (int t = 0; t < 8; ++t) {
                const int k = base + 63 * t;
                const u64 h0 = rl_pair(m[0], k >> 3);
                const u64 h1 = rl_pair(m[1], k >> 3);
                p2[0][0] = pk_fma_s(h0, lo2(wL[t]), p2[0][0]);
                p2[0][1] = pk_fma_s(h0, hi2(wL[t]), p2[0][1]);
                p2[0][2] = pk_fma_s(h0, lo2(wH[t]), p2[0][2]);
                p2[0][3] = pk_fma_s(h0, hi2(wH[t]), p2[0][3]);
                p2[1][0] = pk_fma_s(h1, lo2(wL[t]), p2[1][0]);
                p2[1][1] = pk_fma_s(h1, hi2(wL[t]), p2[1][1]);
                p2[1][2] = pk_fma_s(h1, lo2(wH[t]), p2[1][2]);
                p2[1][3] = pk_fma_s(h1, hi2(wH[t]), p2[1][3]);
            }
            if (h9) {                     // t=8: unit base+504, owner lane 63
                const u64 h0 = rl_pair(m[0], 63);
                const u64 h1 = rl_pair(m[1], 63);
                p2[0][0] = pk_fma_s(h0, lo2(wL[8]), p2[0][0]);
                p2[0][1] = pk_fma_s(h0, hi2(wL[8]), p2[0][1]);
                p2[0][2] = pk_fma_s(h0, lo2(wH[8]), p2[0][2]);
                p2[0][3] = pk_fma_s(h0, hi2(wH[8]), p2[0][3]);
                p2[1][0] = pk_fma_s(h1, lo2(wL[8]), p2[1][0]);
                p2[1][1] = pk_fma_s(h1, hi2(wL[8]), p2[1][1]);
                p2[1][2] = pk_fma_s(h1, lo2(wH[8]), p2[1][2]);
                p2[1][3] = pk_fma_s(h1, hi2(wH[8]), p2[1][3]);
            }

            // (c) one-hot select newly-final h2 (deg==i), add-tree
            float g[2];
            #pragma unroll
            for (int r = 0; r < 2; ++r) {
                float s[8];
                #pragma unroll
                for (int u = 0; u < 8; ++u)
                    s[u] = (deg[u] == i) ? p2[r][u >> 1][u & 1] : 0.f;
                const float sv = ((s[0] + s[1]) + (s[2] + s[3]))
                               + ((s[4] + s[5]) + (s[6] + s[7]));
                g[r] = fmaxf(sv, 0.f);
            }

            // (d) incremental W3 accumulation: one pk_fma per row per t
            // (w3v[t] = {W3[k,lane], W3[k,64+lane]}), even/odd split chains.
            #pragma unroll
            for (int t = 0; t < 8; ++t) {
                const int k = base + 63 * t;
                const u64 h0 = rl_pair(g[0], k >> 3);
                const u64 h1 = rl_pair(g[1], k >> 3);
                if (t & 1) {
                    accB[0] = pk_fma_s(h0, w3v[t], accB[0]);
                    accB[1] = pk_fma_s(h1, w3v[t], accB[1]);
                } else {
                    accA[0] = pk_fma_s(h0, w3v[t], accA[0]);
                    accA[1] = pk_fma_s(h1, w3v[t], accA[1]);
                }
            }
            if (h9) {
                const u64 h0 = rl_pair(g[0], 63);
                const u64 h1 = rl_pair(g[1], 63);
                accB[0] = pk_fma_s(h0, w3v[8], accB[0]);
                accB[1] = pk_fma_s(h1, w3v[8], accB[1]);
            }
        }

        // (e) z_i: column i's totals live in lane i; every lane computes its
        // own candidate (parallel), one readlane extracts; feed back into p1.
        {
            #pragma unroll
            for (int r = 0; r < 2; ++r) {
                const f32x2 at = accA[r] + accB[r];
                const float am = at[0] + b3m;
                const float ap = at[1] + b3p;
                const float sp = fast_softplus(ap);
                const float zc = fmaf(sp, ep[r], am);
                const float zi = bcast(zc, i);
                if (lane == i) z[r] = zi;
                const u64 zp = rl_pair(zc, i);
                p1[r][0] = pk_fma_s(zp, lo2(w1L), p1[r][0]);
                p1[r][1] = pk_fma_s(zp, hi2(w1L), p1[r][1]);
                p1[r][2] = pk_fma_s(zp, lo2(w1H), p1[r][2]);
                p1[r][3] = pk_fma_s(zp, hi2(w1H), p1[r][3]);
            }
        }

        __syncthreads();
    }

    #pragma unroll
    for (int r = 0; r < 2; ++r) out[(rbase + r) * DD + lane] = z[r];
}

extern "C" void kernel_launch(void* const* d_in, const int* in_sizes, int n_in,
                              void* d_out, int out_size, void* d_ws, size_t ws_size,
                              hipStream_t stream) {
    const float* ctx = (const float*)d_in[0];
    const float* eps = (const float*)d_in[1];
    const float* W1  = (const float*)d_in[2];
    const float* b1  = (const float*)d_in[3];
    const float* W2  = (const float*)d_in[4];
    const float* b2  = (const float*)d_in[5];
    const float* W3  = (const float*)d_in[6];
    const float* b3  = (const float*)d_in[7];
    (void)d_ws; (void)ws_size; (void)in_sizes; (void)n_in; (void)out_size;

    made_sample<<<BATCH / 8, 256, 0, stream>>>(ctx, eps, W1, b1, W2, b2, W3, b3,
                                               (float*)d_out);
}

// Round 7
// 185.202 us; speedup vs baseline: 1.0231x; 1.0231x over previous
//
#include <hip/hip_runtime.h>
#include <math.h>

#define DD 64
#define CC 128
#define HH 512
#define BATCH 4096

typedef __attribute__((ext_vector_type(2))) float f32x2;
typedef unsigned long long u64;

__device__ __forceinline__ f32x2 splat2(float x) { f32x2 v; v[0] = x; v[1] = x; return v; }

// packed FMA with the one legal scalar source: src0 is an SGPR pair {h,h}.
__device__ __forceinline__ f32x2 pk_fma_s(u64 hpair, f32x2 b, f32x2 c) {
    f32x2 d;
    asm("v_pk_fma_f32 %0, %1, %2, %3" : "=v"(d) : "s"(hpair), "v"(b), "v"(c));
    return d;
}

__device__ __forceinline__ float fast_softplus(float x) {
    float t = exp2f(-fabsf(x) * 1.44269504f);
    return fmaxf(x, 0.f) + 0.69314718f * log2f(1.f + t);
}

// wave-uniform broadcast via v_readlane (SGPR result)
__device__ __forceinline__ float bcast(float x, int l) {
    return __int_as_float(__builtin_amdgcn_readlane(__float_as_int(x), l));
}
// broadcast to an SGPR pair {x,x} for pk_fma_s (pair build is SALU, co-issues)
__device__ __forceinline__ u64 rl_pair(float x, int l) {
    unsigned u = (unsigned)__builtin_amdgcn_readlane(__float_as_int(x), l);
    return ((u64)u << 32) | u;
}

typedef const __attribute__((address_space(1))) void* as1_cptr;
typedef __attribute__((address_space(3))) void* as3_ptr;
__device__ __forceinline__ void glds16(const float* g, float* l) {
    __builtin_amdgcn_global_load_lds((as1_cptr)g, (as3_ptr)l, 16, 0, 0);
}

// counted vmcnt wait: keep future-buffer staging in flight (NEVER drain to 0
// in the loop — T4). N is wave-uniform; "memory" clobber pins LDS reads below.
#define WAIT_VM(N) asm volatile("s_waitcnt vmcnt(" #N ")" ::: "memory")
#define CFENCE()   asm volatile("" ::: "memory")

// One block = 4 waves x R=2 rows = 8 batch rows; grid 512 -> 2 blocks/CU.
//
// R7 = R6 pipeline + race fix. R6's failure: the W3 pair was read via an
// inline-asm ds_read2_b32 WITHOUT an lgkmcnt wait -- the compiler doesn't
// model asm-load latency, so the consuming FMA read the dest VGPR before the
// DS return (rule-18 hazard; R5 had the explicit wait, R6 dropped it).
// Fix: plain C loads for the W3 pair; the compiler inserts the lgkmcnt wait
// (and fuses the pair into ds_read2_b32 itself). Pipeline unchanged:
//   - 3 LDS buffers, staged 2 iterations ahead via global_load_lds;
//   - per-iter sync = s_waitcnt vmcnt(c_w) + raw s_barrier (no vmcnt(0) drain
//     in the loop); c_w = per-wave glds count for ONE step = {7,7,6,5};
//   - buffer (i+2)%3 == (i-1)%3 is overwritten only after the barrier at i,
//     by which point all waves' reads of it (iteration i-1, data-dependence-
//     forced before that barrier) are complete.
__global__ __launch_bounds__(256, 2) void made_sample(
    const float* __restrict__ ctx,   // (B, C)
    const float* __restrict__ eps,   // (B, D)
    const float* __restrict__ W1,    // (D+C, H)
    const float* __restrict__ b1,    // (H)
    const float* __restrict__ W2,    // (H, H)
    const float* __restrict__ b2,    // (H)
    const float* __restrict__ W3,    // (H, 2D)
    const float* __restrict__ b3,    // (2D)
    float* __restrict__ out)         // (B, D)
{
    const int lane  = threadIdx.x & 63;
    const int w     = threadIdx.x >> 6;          // wave 0..3
    const int rbase = blockIdx.x * 8 + w * 2;    // 2 batch rows per wave
    const int jbase = 8 * lane;

    __shared__ float sbuf[3][10 * HH];           // 3 x 20 KB (9 W2 + 1 W1 slots)
    __shared__ float w3sb[3][5 * 256];           // 3 x 5 KB  (5 W3 pair slots)

    int deg[8];
    #pragma unroll
    for (int u = 0; u < 8; ++u) deg[u] = (jbase + u) % 63 + 1;

    // split-half LDS read: slot base -> 4 f32x2 (8 floats) for this lane
    auto load8v = [&](const float* base_, f32x2* r_) {
        float4 a = *(const float4*)(base_ + lane * 4);
        float4 b = *(const float4*)(base_ + 256 + lane * 4);
        r_[0][0] = a.x; r_[0][1] = a.y; r_[1][0] = a.z; r_[1][1] = a.w;
        r_[2][0] = b.x; r_[2][1] = b.y; r_[3][0] = b.z; r_[3][1] = b.w;
    };
    auto stage_row = [&](const float* src, float* dst) {
        glds16(src + lane * 8,     dst);
        glds16(src + lane * 8 + 4, dst + 256);
    };
    // W3 rows k0,k1 (128 floats each) into one 1KB pair slot:
    // lanes 0..31 carry row k0, lanes 32..63 row k1.
    auto stage_w3pair = [&](int k0, int k1, float* dst) {
        const float* g = (lane < 32) ? (W3 + k0 * (2 * DD) + lane * 4)
                                     : (W3 + k1 * (2 * DD) + (lane - 32) * 4);
        glds16(g, dst);
    };

    f32x2 p1[2][4], p2[2][4];
    #pragma unroll
    for (int j = 0; j < 4; ++j) {
        f32x2 t1, t2;
        t1[0] = b1[jbase + 2 * j]; t1[1] = b1[jbase + 2 * j + 1];
        t2[0] = b2[jbase + 2 * j]; t2[1] = b2[jbase + 2 * j + 1];
        p1[0][j] = t1; p1[1][j] = t1;
        p2[0][j] = t2; p2[1][j] = t2;
    }
    f32x2 accA[2], accB[2];                      // split even/odd-t chains
    accA[0] = splat2(0.f); accA[1] = splat2(0.f);
    accB[0] = splat2(0.f); accB[1] = splat2(0.f);

    float ca[2], cb[2], ep[2];
    #pragma unroll
    for (int r = 0; r < 2; ++r) {
        ca[r] = ctx[(rbase + r) * CC + lane];
        cb[r] = ctx[(rbase + r) * CC + 64 + lane];
        ep[r] = eps[(rbase + r) * DD + lane];
    }
    const float b3m = b3[lane];        // bias for mean col `lane`
    const float b3p = b3[64 + lane];   // bias for prescale col `lane`

    // ctx chunk ch: W1 rows DD+8ch..+7 -> slots 0..7; uniform 4 glds/wave
    auto stage_ctx = [&](int ch, float* buf) {
        stage_row(W1 + (DD + 8 * ch + 2 * w) * HH,     buf + (2 * w) * HH);
        stage_row(W1 + (DD + 8 * ch + 2 * w + 1) * HH, buf + (2 * w + 1) * HH);
    };
    // staging for main step `in`; UNIFORM glds count per wave: {7,7,6,5}.
    // slot-8 / pair-4 rows clamped to 511 when base+504 >= 512 (consumed only
    // under the h9 guard, so the clamped garbage is never used).
    auto stage_step = [&](int in, float* buf, float* w3buf) {
        const int basen = (in == 0) ? 0 : (in - 1);
        const int r8 = (basen + 504 < HH) ? (basen + 504) : (HH - 1);
        stage_row(W2 + (basen + 63 * w) * HH,       buf + w * HH);
        stage_row(W2 + (basen + 63 * (4 + w)) * HH, buf + (4 + w) * HH);
        if (w == 0) stage_row(W2 + r8 * HH, buf + 8 * HH);
        if (w == 1) stage_row(W1 + in * HH, buf + 9 * HH);
        stage_w3pair(basen + 63 * (2 * w), basen + 63 * (2 * w + 1),
                     w3buf + w * 256);
        if (w == 2) stage_w3pair(r8, r8, w3buf + 4 * 256);
    };
    // per-wave outstanding count for ONE future iteration of stage_step
    auto wait_step = [&]() {
        if (w == 0 || w == 1) WAIT_VM(7);
        else if (w == 2)      WAIT_VM(6);
        else                  WAIT_VM(5);
    };

    // ---- context init: pre1 += ctx @ W1[D:,:], 16 chunks, 2-deep pipeline ----
    stage_ctx(0, sbuf[0]);
    stage_ctx(1, sbuf[1]);
    int bc = 0;                                   // buffer index = ch % 3
    #pragma unroll 1
    for (int ch = 0; ch < 16; ++ch) {
        if (ch < 15) WAIT_VM(4); else WAIT_VM(0); // own chunk-ch glds done
        __builtin_amdgcn_s_barrier();             // all waves' staging done;
        CFENCE();                                 // all done reading ch-1
        __builtin_amdgcn_sched_barrier(0);
        const int b2i = (bc < 1) ? bc + 2 : bc - 1;   // (ch+2) % 3
        if (ch < 14) stage_ctx(ch + 2, sbuf[b2i]);
        float* cur = sbuf[bc];
        #pragma unroll
        for (int q = 0; q < 8; ++q) {
            f32x2 cw[4];
            load8v(cur + q * HH, cw);
            const int c = 8 * ch + q;
            #pragma unroll
            for (int r = 0; r < 2; ++r) {
                const u64 cvp = rl_pair((ch < 8) ? ca[r] : cb[r], c & 63);
                #pragma unroll
                for (int j = 0; j < 4; ++j) p1[r][j] = pk_fma_s(cvp, cw[j], p1[r][j]);
            }
        }
        bc = (bc < 2) ? bc + 1 : 0;
    }
    __syncthreads();                              // full drain before re-staging

    float z[2] = {0.f, 0.f};
    stage_step(0, sbuf[0], w3sb[0]);
    stage_step(1, sbuf[1], w3sb[1]);
    bc = 0;                                       // buffer index = i % 3

    // ---- autoregressive main loop: 2-deep counted-vmcnt pipeline ----
    #pragma unroll 1
    for (int i = 0; i < DD; ++i) {
        if (i < 63) wait_step(); else WAIT_VM(0); // own buf-i glds done
        __builtin_amdgcn_s_barrier();             // everyone's buf-i staged;
        CFENCE();                                 // everyone done reading i-1
        __builtin_amdgcn_sched_barrier(0);

        float* cur = sbuf[bc];
        const float* w3s = w3sb[bc];
        const int b2i = (bc < 1) ? bc + 2 : bc - 1;   // (i+2) % 3
        if (i < 62) stage_step(i + 2, sbuf[b2i], w3sb[b2i]);

        if (i > 0) {                      // i==0: no unit has deg==0, all h==0
            const int base = i - 1;
            const bool h9 = base < 8;     // 9th finalizing unit exists (i<=8)

            // (a) one-hot select finalized h1 (deg==i), add-tree
            float m[2];
            #pragma unroll
            for (int r = 0; r < 2; ++r) {
                float s[8];
                #pragma unroll
                for (int u = 0; u < 8; ++u)
                    s[u] = (deg[u] == i) ? p1[r][u >> 1][u & 1] : 0.f;
                const float sv = ((s[0] + s[1]) + (s[2] + s[3]))
                               + ((s[4] + s[5]) + (s[6] + s[7]));
                m[r] = fmaxf(sv, 0.f);
            }

            // (b) rank update of pre2 (packed FMA, SGPR-pair h operand);
            // loads inline -> compiler interleaves ds_read with FMA (R2 style)
            #pragma unroll
            for (int t = 0; t < 8; ++t) {
                const int k = base + 63 * t;
                f32x2 wv[4];
                load8v(cur + t * HH, wv);
                const u64 h0 = rl_pair(m[0], k >> 3);
                const u64 h1 = rl_pair(m[1], k >> 3);
                #pragma unroll
                for (int j = 0; j < 4; ++j) {
                    p2[0][j] = pk_fma_s(h0, wv[j], p2[0][j]);
                    p2[1][j] = pk_fma_s(h1, wv[j], p2[1][j]);
                }
            }
            if (h9) {                     // t=8: unit base+504, owner lane 63
                f32x2 wv[4];
                load8v(cur + 8 * HH, wv);
                const u64 h0 = rl_pair(m[0], 63);
                const u64 h1 = rl_pair(m[1], 63);
                #pragma unroll
                for (int j = 0; j < 4; ++j) {
                    p2[0][j] = pk_fma_s(h0, wv[j], p2[0][j]);
                    p2[1][j] = pk_fma_s(h1, wv[j], p2[1][j]);
                }
            }

            // (c) one-hot select newly-final h2 (deg==i), add-tree
            float g[2];
            #pragma unroll
            for (int r = 0; r < 2; ++r) {
                float s[8];
                #pragma unroll
                for (int u = 0; u < 8; ++u)
                    s[u] = (deg[u] == i) ? p2[r][u >> 1][u & 1] : 0.f;
                const float sv = ((s[0] + s[1]) + (s[2] + s[3]))
                               + ((s[4] + s[5]) + (s[6] + s[7]));
                g[r] = fmaxf(sv, 0.f);
            }

            // (d) incremental W3 accumulation. PLAIN C loads (R6 bug fix):
            // compiler tracks them, inserts the lgkmcnt wait before use, and
            // fuses the pair into ds_read2_b32 itself.
            #pragma unroll
            for (int t = 0; t < 8; ++t) {
                const int k = base + 63 * t;
                f32x2 w3v;
                w3v[0] = w3s[t * 128 + lane];        // W3[k_t, lane]
                w3v[1] = w3s[t * 128 + 64 + lane];   // W3[k_t, 64+lane]
                const u64 h0 = rl_pair(g[0], k >> 3);
                const u64 h1 = rl_pair(g[1], k >> 3);
                if (t & 1) {
                    accB[0] = pk_fma_s(h0, w3v, accB[0]);
                    accB[1] = pk_fma_s(h1, w3v, accB[1]);
                } else {
                    accA[0] = pk_fma_s(h0, w3v, accA[0]);
                    accA[1] = pk_fma_s(h1, w3v, accA[1]);
                }
            }
            if (h9) {
                f32x2 w3v;
                w3v[0] = w3s[8 * 128 + lane];
                w3v[1] = w3s[8 * 128 + 64 + lane];
                const u64 h0 = rl_pair(g[0], 63);
                const u64 h1 = rl_pair(g[1], 63);
                accB[0] = pk_fma_s(h0, w3v, accB[0]);
                accB[1] = pk_fma_s(h1, w3v, accB[1]);
            }
        }

        // (e) z_i: column i's totals live in lane i; every lane computes its
        // own candidate (parallel), one readlane extracts; feed back into p1.
        {
            f32x2 w1v[4];
            load8v(cur + 9 * HH, w1v);
            #pragma unroll
            for (int r = 0; r < 2; ++r) {
                const f32x2 at = accA[r] + accB[r];
                const float am = at[0] + b3m;
                const float ap = at[1] + b3p;
                const float sp = fast_softplus(ap);
                const float zc = fmaf(sp, ep[r], am);
                const float zi = bcast(zc, i);
                if (lane == i) z[r] = zi;
                const u64 zp = rl_pair(zc, i);
                #pragma unroll
                for (int j = 0; j < 4; ++j) p1[r][j] = pk_fma_s(zp, w1v[j], p1[r][j]);
            }
        }

        bc = (bc < 2) ? bc + 1 : 0;
        // no trailing barrier: next iteration's wait+barrier provides the sync
    }

    #pragma unroll
    for (int r = 0; r < 2; ++r) out[(rbase + r) * DD + lane] = z[r];
}

extern "C" void kernel_launch(void* const* d_in, const int* in_sizes, int n_in,
                              void* d_out, int out_size, void* d_ws, size_t ws_size,
                              hipStream_t stream) {
    const float* ctx = (const float*)d_in[0];
    const float* eps = (const float*)d_in[1];
    const float* W1  = (const float*)d_in[2];
    const float* b1  = (const float*)d_in[3];
    const float* W2  = (const float*)d_in[4];
    const float* b2  = (const float*)d_in[5];
    const float* W3  = (const float*)d_in[6];
    const float* b3  = (const float*)d_in[7];
    (void)d_ws; (void)ws_size; (void)in_sizes; (void)n_in; (void)out_size;

    made_sample<<<BATCH / 8, 256, 0, stream>>>(ctx, eps, W1, b1, W2, b2, W3, b3,
                                               (float*)d_out);
}